// Round 14
// baseline (126.037 us; speedup 1.0000x reference)
//
#include <hip/hip_runtime.h>

#define N_NODES   20000
#define N_ANCHORS 64
#define D         128
#define N_EDGES   (N_NODES * N_ANCHORS)
#define NCHUNK    4
#define CDIM      32          // dims per chunk

typedef float f32x2  __attribute__((ext_vector_type(2)));
typedef float f32x4  __attribute__((ext_vector_type(4)));
typedef short bf16x8 __attribute__((ext_vector_type(8)));

static __device__ __forceinline__ unsigned short f32_to_bf16(float x) {
    unsigned int u = __float_as_uint(x);
    u += 0x7FFFu + ((u >> 16) & 1u);   // RNE
    return (unsigned short)(u >> 16);
}
static __device__ __forceinline__ f32x2 bf2(unsigned int w) {
    f32x2 r;
    r.x = __uint_as_float(w << 16);
    r.y = __uint_as_float(w & 0xFFFF0000u);
    return r;
}

// ---------------- Kernel A (merged prep): pack | wcvt | prefill
#define NB_PACK    (N_EDGES / 256)            // 5000
#define NB_WCVT    ((D * D) / 256)            // 64
#define NB_PREFILL (N_EDGES / 1024)           // 1250
__global__ __launch_bounds__(256) void prep_kernel(
    const int* __restrict__ src, const int* __restrict__ dst,
    const float* __restrict__ sp_dist,
    const float* __restrict__ Wu, const float* __restrict__ Wv,
    const float* __restrict__ bpos,
    unsigned long long* __restrict__ epack,
    unsigned short* __restrict__ Wt_u, unsigned short* __restrict__ Wt_v,
    float* __restrict__ out_pos)
{
    const int bid = blockIdx.x;
    if (bid < NB_PACK) {
        const int e = bid * 256 + threadIdx.x;
        const unsigned int s = (unsigned int)__builtin_nontemporal_load(&src[e]);
        const unsigned int d = (unsigned int)__builtin_nontemporal_load(&dst[e]);
        const float       sp = __builtin_nontemporal_load(&sp_dist[e]);
        epack[e] = (unsigned long long)(s | (d << 15)) |
                   ((unsigned long long)__float_as_uint(sp) << 32);
    } else if (bid < NB_PACK + NB_WCVT) {
        const int t = (bid - NB_PACK) * 256 + threadIdx.x;   // 0..16383
        const int k = t >> 7, j = t & 127;
        Wt_u[j * D + k] = f32_to_bf16(Wu[t]);
        Wt_v[j * D + k] = f32_to_bf16(Wv[t]);
    } else {
        const int i = (bid - NB_PACK - NB_WCVT) * 256 + threadIdx.x;
        const float bp = bpos[0];
        f32x4 v = {bp, bp, bp, bp};
        __builtin_nontemporal_store(v, (f32x4*)out_pos + i);
    }
}

// ---------------- Kernel 1: meta[e] = epack[anchor_eid[e]] — ONE 8B gather
__global__ __launch_bounds__(256) void meta_kernel(
    const unsigned long long* __restrict__ epack,
    const int* __restrict__ anchor_eid,
    unsigned long long* __restrict__ meta)
{
    const int e = blockIdx.x * 256 + threadIdx.x;
    const int eid = __builtin_nontemporal_load(&anchor_eid[e]);
    const unsigned long long m = epack[eid];
    __builtin_nontemporal_store(m, &meta[e]);
}

// ---------------- Kernel 2: MFMA projections -> bf16 chunk-major u_c/v_c.
// mfma_f32_16x16x32_bf16 layout (m89):
//   A[row=l&15][k=(l>>4)*8+e], B[k=(l>>4)*8+e][col=l&15],
//   D[row=(l>>4)*4+r][col=l&15]
__global__ __launch_bounds__(256) void proj_mfma_kernel(
    const float* __restrict__ feature,
    const unsigned short* __restrict__ Wt_u,
    const unsigned short* __restrict__ Wt_v,
    const float* __restrict__ bu, const float* __restrict__ bv,
    unsigned short* __restrict__ u_c, unsigned short* __restrict__ v_c)
{
    const int wave = threadIdx.x >> 6;
    const int lane = threadIdx.x & 63;
    const int n0   = blockIdx.x * 16;        // 1250 blocks exact
    const int mat    = wave & 1;             // 0=u, 1=v
    const int ctbase = (wave >> 1) * 4;      // col-tiles [ctbase, ctbase+4)

    const int row = lane & 15;
    const int kq  = lane >> 4;               // 0..3

    bf16x8 afrag[4];
    #pragma unroll
    for (int kt = 0; kt < 4; ++kt) {
        const float* fp = feature + (size_t)(n0 + row) * D + kt * 32 + kq * 8;
        const f32x4 f0 = *(const f32x4*)fp;
        const f32x4 f1 = *(const f32x4*)(fp + 4);
        bf16x8 a;
        #pragma unroll
        for (int e = 0; e < 4; ++e) a[e]     = (short)f32_to_bf16(f0[e]);
        #pragma unroll
        for (int e = 0; e < 4; ++e) a[4 + e] = (short)f32_to_bf16(f1[e]);
        afrag[kt] = a;
    }

    const unsigned short* Wt   = mat ? Wt_v : Wt_u;
    const float*          bias = mat ? bv   : bu;
    unsigned short*       outp = mat ? v_c  : u_c;

    #pragma unroll
    for (int t = 0; t < 4; ++t) {
        const int ct = ctbase + t;
        const int j  = ct * 16 + row;
        f32x4 acc = {0.f, 0.f, 0.f, 0.f};
        #pragma unroll
        for (int kt = 0; kt < 4; ++kt) {
            const bf16x8 b = *(const bf16x8*)(Wt + (size_t)j * D + kt * 32 + kq * 8);
            acc = __builtin_amdgcn_mfma_f32_16x16x32_bf16(afrag[kt], b, acc, 0, 0, 0);
        }
        const float bj  = bias[j];
        const int  cj   = ct >> 1;
        const int  dimc = (ct & 1) * 16 + row;
        #pragma unroll
        for (int r = 0; r < 4; ++r) {
            const int n = n0 + kq * 4 + r;
            outp[((size_t)cj * N_NODES + n) * CDIM + dimc] = f32_to_bf16(acc[r] + bj);
        }
    }
}

// ---------------- Kernel 3: FUSED chunk passes, XCD-pinned (structural floor:
// 2 random 64B lines/edge at the measured ~8 lines/cyc/XCD L2 service rate;
// depth-8 issue experiments R11-R13 all null).
__global__ __launch_bounds__(256) void fused_chunk_kernel(
    const unsigned short* __restrict__ u_c, const unsigned short* __restrict__ v_c,
    const unsigned long long* __restrict__ meta,
    const float* __restrict__ Wpos,
    float* __restrict__ out_pos, float* __restrict__ out_struct)
{
    const int bid   = blockIdx.x;            // 20000 blocks
    const int x     = bid & 7;               // XCD guess
    const int chunk = x >> 1;
    const int half  = x & 1;
    const int nb    = bid >> 3;              // 0..2499
    const int wave  = threadIdx.x >> 6;
    const int lane  = threadIdx.x & 63;
    const int n     = half * 10000 + nb * 4 + wave;

    const int sub = lane & 3;                 // dims [sub*8, sub*8+8) of chunk
    const int grp = lane >> 2;                // anchor sub-slot 0..15

    const unsigned long long mm =
        __builtin_nontemporal_load(&meta[(size_t)n * N_ANCHORS + lane]);
    const int   s  = (int)(mm & 0x7FFFu);
    const int   d  = (int)((mm >> 15) & 0x7FFFu);
    const float sp = __uint_as_float((unsigned int)(mm >> 32));

    f32x2 wp[4];
    {
        const f32x2* wpp = (const f32x2*)(Wpos + chunk * CDIM + sub * 8);
        #pragma unroll
        for (int q = 0; q < 4; ++q) wp[q] = wpp[q];
    }

    const unsigned short* ub = u_c + (size_t)chunk * N_NODES * CDIM;
    const unsigned short* vb = v_c + (size_t)chunk * N_NODES * CDIM;

    f32x2 acc0 = {0.f, 0.f}, acc1 = {0.f, 0.f}, acc2 = {0.f, 0.f}, acc3 = {0.f, 0.f};
    const f32x2 zero2 = {0.f, 0.f};

    __shared__ float posbuf[4][N_ANCHORS];

    #pragma unroll
    for (int it = 0; it < 4; ++it) {
        const int a = it * 16 + grp;
        const int   sa  = __shfl(s,  a);
        const int   da  = __shfl(d,  a);
        const float spa = __shfl(sp, a);

        const uint4 uu = *(const uint4*)(ub + (size_t)sa * CDIM + sub * 8);
        const uint4 vv = *(const uint4*)(vb + (size_t)da * CDIM + sub * 8);

        f32x2 m0 = bf2(uu.x) * spa + bf2(vv.x);
        f32x2 m1 = bf2(uu.y) * spa + bf2(vv.y);
        f32x2 m2 = bf2(uu.z) * spa + bf2(vv.z);
        f32x2 m3 = bf2(uu.w) * spa + bf2(vv.w);
        m0 = __builtin_elementwise_max(m0, zero2);
        m1 = __builtin_elementwise_max(m1, zero2);
        m2 = __builtin_elementwise_max(m2, zero2);
        m3 = __builtin_elementwise_max(m3, zero2);

        acc0 += m0; acc1 += m1; acc2 += m2; acc3 += m3;

        f32x2 pd = m0 * wp[0] + m1 * wp[1] + m2 * wp[2] + m3 * wp[3];
        float p = pd.x + pd.y;
        p += __shfl_xor(p, 2);
        p += __shfl_xor(p, 1);
        if (sub == 0) posbuf[wave][a] = p;
    }

    float acc[8] = {acc0.x, acc0.y, acc1.x, acc1.y, acc2.x, acc2.y, acc3.x, acc3.y};
    #pragma unroll
    for (int k = 0; k < 8; ++k) {
        acc[k] += __shfl_xor(acc[k], 4);
        acc[k] += __shfl_xor(acc[k], 8);
        acc[k] += __shfl_xor(acc[k], 16);
        acc[k] += __shfl_xor(acc[k], 32);
    }

    // posbuf[wave][*] is same-wave only — no barrier needed.

    atomicAdd(&out_pos[(size_t)n * N_ANCHORS + lane], posbuf[wave][lane]);

    if (grp == 0) {
        const float inv = 1.0f / (float)N_ANCHORS;
        f32x4 o0, o1;
        o0.x = acc[0] * inv; o0.y = acc[1] * inv; o0.z = acc[2] * inv; o0.w = acc[3] * inv;
        o1.x = acc[4] * inv; o1.y = acc[5] * inv; o1.z = acc[6] * inv; o1.w = acc[7] * inv;
        float* os = out_struct + (size_t)n * D + chunk * CDIM + sub * 8;
        __builtin_nontemporal_store(o0, (f32x4*)os);
        __builtin_nontemporal_store(o1, (f32x4*)(os + 4));
    }
}

extern "C" void kernel_launch(void* const* d_in, const int* in_sizes, int n_in,
                              void* d_out, int out_size, void* d_ws, size_t ws_size,
                              hipStream_t stream) {
    const float* feature    = (const float*)d_in[0];
    const float* sp_dist    = (const float*)d_in[1];
    const float* Wu         = (const float*)d_in[2];
    const float* bu         = (const float*)d_in[3];
    const float* Wv         = (const float*)d_in[4];
    const float* bv         = (const float*)d_in[5];
    const float* Wpos       = (const float*)d_in[6];
    const float* bpos       = (const float*)d_in[7];
    const int*   src        = (const int*)d_in[8];
    const int*   dst        = (const int*)d_in[9];
    const int*   anchor_eid = (const int*)d_in[10];

    // ws layout (20.48 MB):
    //   region X [0, 10.24 MB): epack first, then overwritten by u_c|v_c
    //   region Y [10.24, 20.48 MB): meta
    unsigned short* u_c = (unsigned short*)d_ws;
    unsigned short* v_c = u_c + (size_t)NCHUNK * N_NODES * CDIM;
    unsigned long long* epack = (unsigned long long*)d_ws;   // aliases u_c/v_c
    unsigned long long* meta =
        (unsigned long long*)((char*)d_ws + (size_t)2 * NCHUNK * N_NODES * CDIM * 2);

    float* out_pos    = (float*)d_out;
    float* out_struct = out_pos + (size_t)N_EDGES;

    unsigned short* Wt_u = (unsigned short*)out_struct;
    unsigned short* Wt_v = Wt_u + D * D;

    prep_kernel<<<NB_PACK + NB_WCVT + NB_PREFILL, 256, 0, stream>>>(
        src, dst, sp_dist, Wu, Wv, bpos, epack, Wt_u, Wt_v, out_pos);
    meta_kernel<<<N_EDGES / 256, 256, 0, stream>>>(epack, anchor_eid, meta);
    proj_mfma_kernel<<<N_NODES / 16, 256, 0, stream>>>(feature, Wt_u, Wt_v,
                                                       bu, bv, u_c, v_c);
    fused_chunk_kernel<<<N_NODES * NCHUNK / 4, 256, 0, stream>>>(
        u_c, v_c, meta, Wpos, out_pos, out_struct);
}

// Round 15
// 108.492 us; speedup vs baseline: 1.1617x; 1.1617x over previous
//
#include <hip/hip_runtime.h>

#define N_NODES   20000
#define N_ANCHORS 64
#define D         128
#define N_EDGES   (N_NODES * N_ANCHORS)
#define NCHUNK    4
#define CDIM      32          // dims per chunk

typedef float f32x2  __attribute__((ext_vector_type(2)));
typedef float f32x4  __attribute__((ext_vector_type(4)));
typedef short bf16x8 __attribute__((ext_vector_type(8)));

static __device__ __forceinline__ unsigned short f32_to_bf16(float x) {
    unsigned int u = __float_as_uint(x);
    u += 0x7FFFu + ((u >> 16) & 1u);   // RNE
    return (unsigned short)(u >> 16);
}
static __device__ __forceinline__ f32x2 bf2(unsigned int w) {
    f32x2 r;
    r.x = __uint_as_float(w << 16);
    r.y = __uint_as_float(w & 0xFFFF0000u);
    return r;
}

// ---------------- Kernel A (merged prep): pack | wcvt | prefill
// epack now lives in the OUT_STRUCT region (dead until fused overwrites it).
#define NB_PACK    (N_EDGES / 256)            // 5000
#define NB_WCVT    ((D * D) / 256)            // 64
#define NB_PREFILL (N_EDGES / 1024)           // 1250
__global__ __launch_bounds__(256) void prep_kernel(
    const int* __restrict__ src, const int* __restrict__ dst,
    const float* __restrict__ sp_dist,
    const float* __restrict__ Wu, const float* __restrict__ Wv,
    const float* __restrict__ bpos,
    unsigned long long* __restrict__ epack,
    unsigned short* __restrict__ Wt_u, unsigned short* __restrict__ Wt_v,
    float* __restrict__ out_pos)
{
    const int bid = blockIdx.x;
    if (bid < NB_PACK) {
        const int e = bid * 256 + threadIdx.x;
        const unsigned int s = (unsigned int)__builtin_nontemporal_load(&src[e]);
        const unsigned int d = (unsigned int)__builtin_nontemporal_load(&dst[e]);
        const float       sp = __builtin_nontemporal_load(&sp_dist[e]);
        epack[e] = (unsigned long long)(s | (d << 15)) |
                   ((unsigned long long)__float_as_uint(sp) << 32);
    } else if (bid < NB_PACK + NB_WCVT) {
        const int t = (bid - NB_PACK) * 256 + threadIdx.x;   // 0..16383
        const int k = t >> 7, j = t & 127;
        Wt_u[j * D + k] = f32_to_bf16(Wu[t]);
        Wt_v[j * D + k] = f32_to_bf16(Wv[t]);
    } else {
        const int i = (bid - NB_PACK - NB_WCVT) * 256 + threadIdx.x;
        const float bp = bpos[0];
        f32x4 v = {bp, bp, bp, bp};
        __builtin_nontemporal_store(v, (f32x4*)out_pos + i);
    }
}

// ---------------- Kernel B (mega): proj (bid<1250) ∥ meta (bid>=1250).
// Disjoint buffers: proj reads feature + Wt(regY tail), writes u_c/v_c(regX);
// meta reads epack(out_struct region) + anchor_eid, writes meta_sd/sp(regY).
// proj blocks first so MFMA compute overlaps meta's memory stalls.
// mfma_f32_16x16x32_bf16 layout (m89):
//   A[row=l&15][k=(l>>4)*8+e], B[k=(l>>4)*8+e][col=l&15],
//   D[row=(l>>4)*4+r][col=l&15]
#define NB_PROJ (N_NODES / 16)                // 1250
#define NB_META (N_EDGES / 256)               // 5000
__global__ __launch_bounds__(256) void mega_kernel(
    const float* __restrict__ feature,
    const unsigned short* __restrict__ Wt_u,
    const unsigned short* __restrict__ Wt_v,
    const float* __restrict__ bu, const float* __restrict__ bv,
    unsigned short* __restrict__ u_c, unsigned short* __restrict__ v_c,
    const unsigned long long* __restrict__ epack,
    const int* __restrict__ anchor_eid,
    unsigned int* __restrict__ meta_sd,
    unsigned short* __restrict__ meta_sp)
{
    const int bid = blockIdx.x;
    if (bid >= NB_PROJ) {
        // ---- meta part: one 8B random gather, compressed 6B output
        const int e = (bid - NB_PROJ) * 256 + threadIdx.x;
        const int eid = __builtin_nontemporal_load(&anchor_eid[e]);
        const unsigned long long m = epack[eid];
        const float sp = __uint_as_float((unsigned int)(m >> 32));
        __builtin_nontemporal_store((unsigned int)m, &meta_sd[e]);
        __builtin_nontemporal_store(f32_to_bf16(sp), &meta_sp[e]);
        return;
    }

    // ---- proj part
    const int wave = threadIdx.x >> 6;
    const int lane = threadIdx.x & 63;
    const int n0   = bid * 16;
    const int mat    = wave & 1;             // 0=u, 1=v
    const int ctbase = (wave >> 1) * 4;      // col-tiles [ctbase, ctbase+4)

    const int row = lane & 15;
    const int kq  = lane >> 4;               // 0..3

    bf16x8 afrag[4];
    #pragma unroll
    for (int kt = 0; kt < 4; ++kt) {
        const float* fp = feature + (size_t)(n0 + row) * D + kt * 32 + kq * 8;
        const f32x4 f0 = *(const f32x4*)fp;
        const f32x4 f1 = *(const f32x4*)(fp + 4);
        bf16x8 a;
        #pragma unroll
        for (int e = 0; e < 4; ++e) a[e]     = (short)f32_to_bf16(f0[e]);
        #pragma unroll
        for (int e = 0; e < 4; ++e) a[4 + e] = (short)f32_to_bf16(f1[e]);
        afrag[kt] = a;
    }

    const unsigned short* Wt   = mat ? Wt_v : Wt_u;
    const float*          bias = mat ? bv   : bu;
    unsigned short*       outp = mat ? v_c  : u_c;

    #pragma unroll
    for (int t = 0; t < 4; ++t) {
        const int ct = ctbase + t;
        const int j  = ct * 16 + row;
        f32x4 acc = {0.f, 0.f, 0.f, 0.f};
        #pragma unroll
        for (int kt = 0; kt < 4; ++kt) {
            const bf16x8 b = *(const bf16x8*)(Wt + (size_t)j * D + kt * 32 + kq * 8);
            acc = __builtin_amdgcn_mfma_f32_16x16x32_bf16(afrag[kt], b, acc, 0, 0, 0);
        }
        const float bj  = bias[j];
        const int  cj   = ct >> 1;
        const int  dimc = (ct & 1) * 16 + row;
        #pragma unroll
        for (int r = 0; r < 4; ++r) {
            const int n = n0 + kq * 4 + r;
            outp[((size_t)cj * N_NODES + n) * CDIM + dimc] = f32_to_bf16(acc[r] + bj);
        }
    }
}

// ---------------- Kernel 3: FUSED chunk passes, XCD-pinned, asm deep-issue
// (R13 variant measured ~4us faster than plain loads). Structural floor:
// 2 random 64B lines/edge at ~8 lines/cyc/XCD L2 service rate.
__global__ __launch_bounds__(256) void fused_chunk_kernel(
    const unsigned short* __restrict__ u_c, const unsigned short* __restrict__ v_c,
    const unsigned int* __restrict__ meta_sd,
    const unsigned short* __restrict__ meta_sp,
    const float* __restrict__ Wpos,
    float* __restrict__ out_pos, float* __restrict__ out_struct)
{
    const int bid   = blockIdx.x;            // 20000 blocks
    const int x     = bid & 7;               // XCD guess
    const int chunk = x >> 1;
    const int half  = x & 1;
    const int nb    = bid >> 3;              // 0..2499
    const int wave  = threadIdx.x >> 6;
    const int lane  = threadIdx.x & 63;
    const int n     = half * 10000 + nb * 4 + wave;

    const int sub = lane & 3;                 // dims [sub*8, sub*8+8) of chunk
    const int grp = lane >> 2;                // anchor sub-slot 0..15

    // per-lane meta for anchor `lane` — coalesced 256B + 128B wave loads
    const unsigned int   sd  = __builtin_nontemporal_load(&meta_sd[(size_t)n * N_ANCHORS + lane]);
    const unsigned short spw = __builtin_nontemporal_load(&meta_sp[(size_t)n * N_ANCHORS + lane]);
    const int   s  = (int)(sd & 0x7FFFu);
    const int   d  = (int)((sd >> 15) & 0x7FFFu);
    const float sp = __uint_as_float((unsigned int)spw << 16);

    f32x2 wp[4];
    {
        const f32x2* wpp = (const f32x2*)(Wpos + chunk * CDIM + sub * 8);
        #pragma unroll
        for (int q = 0; q < 4; ++q) wp[q] = wpp[q];
    }

    const unsigned short* ub = u_c + (size_t)chunk * N_NODES * CDIM;
    const unsigned short* vb = v_c + (size_t)chunk * N_NODES * CDIM;

    f32x2 acc0 = {0.f, 0.f}, acc1 = {0.f, 0.f}, acc2 = {0.f, 0.f}, acc3 = {0.f, 0.f};
    const f32x2 zero2 = {0.f, 0.f};

    __shared__ float posbuf[4][N_ANCHORS];

    // -------- ISSUE phase: all 8 gathers via inline asm, one vmcnt drain
    uint4 ubuf[4], vbuf[4];
    {
        const unsigned short* ua[4];
        const unsigned short* va[4];
        #pragma unroll
        for (int it = 0; it < 4; ++it) {
            const int a = it * 16 + grp;
            const int sa = __shfl(s, a);
            const int da = __shfl(d, a);
            ua[it] = ub + (size_t)sa * CDIM + sub * 8;
            va[it] = vb + (size_t)da * CDIM + sub * 8;
        }
        #pragma unroll
        for (int it = 0; it < 4; ++it) {
            asm volatile("global_load_dwordx4 %0, %1, off"
                         : "=v"(ubuf[it]) : "v"(ua[it]));
            asm volatile("global_load_dwordx4 %0, %1, off"
                         : "=v"(vbuf[it]) : "v"(va[it]));
        }
        asm volatile("s_waitcnt vmcnt(0)" ::: "memory");
        __builtin_amdgcn_sched_barrier(0);   // rule #18
    }

    // -------- CONSUME phase
    #pragma unroll
    for (int it = 0; it < 4; ++it) {
        const int a = it * 16 + grp;
        const float spa = __shfl(sp, a);
        const uint4 uu = ubuf[it];
        const uint4 vv = vbuf[it];

        f32x2 m0 = bf2(uu.x) * spa + bf2(vv.x);
        f32x2 m1 = bf2(uu.y) * spa + bf2(vv.y);
        f32x2 m2 = bf2(uu.z) * spa + bf2(vv.z);
        f32x2 m3 = bf2(uu.w) * spa + bf2(vv.w);
        m0 = __builtin_elementwise_max(m0, zero2);
        m1 = __builtin_elementwise_max(m1, zero2);
        m2 = __builtin_elementwise_max(m2, zero2);
        m3 = __builtin_elementwise_max(m3, zero2);

        acc0 += m0; acc1 += m1; acc2 += m2; acc3 += m3;

        f32x2 pd = m0 * wp[0] + m1 * wp[1] + m2 * wp[2] + m3 * wp[3];
        float p = pd.x + pd.y;
        p += __shfl_xor(p, 2);
        p += __shfl_xor(p, 1);
        if (sub == 0) posbuf[wave][a] = p;
    }

    float acc[8] = {acc0.x, acc0.y, acc1.x, acc1.y, acc2.x, acc2.y, acc3.x, acc3.y};
    #pragma unroll
    for (int k = 0; k < 8; ++k) {
        acc[k] += __shfl_xor(acc[k], 4);
        acc[k] += __shfl_xor(acc[k], 8);
        acc[k] += __shfl_xor(acc[k], 16);
        acc[k] += __shfl_xor(acc[k], 32);
    }

    // posbuf[wave][*] is same-wave only — no barrier needed.

    atomicAdd(&out_pos[(size_t)n * N_ANCHORS + lane], posbuf[wave][lane]);

    if (grp == 0) {
        const float inv = 1.0f / (float)N_ANCHORS;
        f32x4 o0, o1;
        o0.x = acc[0] * inv; o0.y = acc[1] * inv; o0.z = acc[2] * inv; o0.w = acc[3] * inv;
        o1.x = acc[4] * inv; o1.y = acc[5] * inv; o1.z = acc[6] * inv; o1.w = acc[7] * inv;
        float* os = out_struct + (size_t)n * D + chunk * CDIM + sub * 8;
        __builtin_nontemporal_store(o0, (f32x4*)os);
        __builtin_nontemporal_store(o1, (f32x4*)(os + 4));
    }
}

extern "C" void kernel_launch(void* const* d_in, const int* in_sizes, int n_in,
                              void* d_out, int out_size, void* d_ws, size_t ws_size,
                              hipStream_t stream) {
    const float* feature    = (const float*)d_in[0];
    const float* sp_dist    = (const float*)d_in[1];
    const float* Wu         = (const float*)d_in[2];
    const float* bu         = (const float*)d_in[3];
    const float* Wv         = (const float*)d_in[4];
    const float* bv         = (const float*)d_in[5];
    const float* Wpos       = (const float*)d_in[6];
    const float* bpos       = (const float*)d_in[7];
    const int*   src        = (const int*)d_in[8];
    const int*   dst        = (const int*)d_in[9];
    const int*   anchor_eid = (const int*)d_in[10];

    // ws layout (20.48 MB):
    //   region X [0, 10.24 MB):        u_c | v_c        (mega-proj -> fused)
    //   region Y [10.24, 20.48 MB):    meta_sd (5.12MB) | meta_sp (2.56MB) |
    //                                  Wt_u (32KB) | Wt_v (32KB) | spare
    // out_struct region (d_out+N_EDGES, 10.24MB): epack (prep -> mega-meta),
    //   then fully overwritten by fused's struct stores.
    unsigned short* u_c = (unsigned short*)d_ws;
    unsigned short* v_c = u_c + (size_t)NCHUNK * N_NODES * CDIM;

    char* regY = (char*)d_ws + (size_t)2 * NCHUNK * N_NODES * CDIM * 2; // +10.24MB
    unsigned int*   meta_sd = (unsigned int*)regY;
    unsigned short* meta_sp = (unsigned short*)(regY + (size_t)N_EDGES * 4);
    unsigned short* Wt_u    = (unsigned short*)(regY + (size_t)N_EDGES * 6);
    unsigned short* Wt_v    = Wt_u + D * D;

    float* out_pos    = (float*)d_out;
    float* out_struct = out_pos + (size_t)N_EDGES;
    unsigned long long* epack = (unsigned long long*)out_struct;  // 10.24MB exact

    prep_kernel<<<NB_PACK + NB_WCVT + NB_PREFILL, 256, 0, stream>>>(
        src, dst, sp_dist, Wu, Wv, bpos, epack, Wt_u, Wt_v, out_pos);
    mega_kernel<<<NB_PROJ + NB_META, 256, 0, stream>>>(
        feature, Wt_u, Wt_v, bu, bv, u_c, v_c, epack, anchor_eid,
        meta_sd, meta_sp);
    fused_chunk_kernel<<<N_NODES * NCHUNK / 4, 256, 0, stream>>>(
        u_c, v_c, meta_sd, meta_sp, Wpos, out_pos, out_struct);
}